// Round 1
// baseline (445.040 us; speedup 1.0000x reference)
//
#include <hip/hip_runtime.h>

#define B_ 8
#define L_ 2048
#define D_ 128

static __device__ __forceinline__ float4 ld4(const float* p) { return *(const float4*)p; }

// K1: e' = exp((q . v^T) * scale), unnormalized, written to attn region.
// Per-row partial sums (over this block's j-half) written to lpart.
// Grid: B * 32 i-tiles * 2 j-halves = 512 blocks, 256 threads.
// LDS k-major layout -> conflict-free (broadcast) fragment reads.
__global__ __launch_bounds__(256) void score_exp_kernel(
    const float* __restrict__ q, const float* __restrict__ v,
    float* __restrict__ attn, float* __restrict__ lpart)
{
    __shared__ float qs[128 * 64];  // [k][i]
    __shared__ float vs[128 * 64];  // [k][j]
    const int tid = threadIdx.x;
    const int b  = blockIdx.x >> 6;
    const int it = (blockIdx.x >> 1) & 31;
    const int jh = blockIdx.x & 1;
    const int i0 = it * 64;
    const int r = tid & 63, kq = tid >> 6;

    const float* qb = q + (size_t)(b * L_ + i0) * D_;
    #pragma unroll
    for (int c = 0; c < 8; ++c) {
        const int kk = (kq + c * 4) * 4;
        const float4 t = ld4(qb + r * D_ + kk);
        qs[(kk + 0) * 64 + r] = t.x;
        qs[(kk + 1) * 64 + r] = t.y;
        qs[(kk + 2) * 64 + r] = t.z;
        qs[(kk + 3) * 64 + r] = t.w;
    }

    const int tx = tid & 15, ty = tid >> 4;
    float lacc[4] = {0.f, 0.f, 0.f, 0.f};
    const float* vb = v + (size_t)b * L_ * D_;
    float* ab = attn + (size_t)b * L_ * L_;
    const float scale = 0.08838834764831845f;  // 1/sqrt(128)

    for (int jt = jh * 16; jt < jh * 16 + 16; ++jt) {
        __syncthreads();  // previous iter's readers done before overwriting vs
        #pragma unroll
        for (int c = 0; c < 8; ++c) {
            const int kk = (kq + c * 4) * 4;
            const float4 t = ld4(vb + (size_t)(jt * 64 + r) * D_ + kk);
            vs[(kk + 0) * 64 + r] = t.x;
            vs[(kk + 1) * 64 + r] = t.y;
            vs[(kk + 2) * 64 + r] = t.z;
            vs[(kk + 3) * 64 + r] = t.w;
        }
        __syncthreads();

        float acc[4][4];
        #pragma unroll
        for (int a = 0; a < 4; ++a)
            #pragma unroll
            for (int c = 0; c < 4; ++c) acc[a][c] = 0.f;

        #pragma unroll 8
        for (int k = 0; k < 128; ++k) {
            const float4 qv = ld4(qs + k * 64 + ty * 4);
            const float4 vv = ld4(vs + k * 64 + tx * 4);
            const float qa[4] = {qv.x, qv.y, qv.z, qv.w};
            const float va[4] = {vv.x, vv.y, vv.z, vv.w};
            #pragma unroll
            for (int a = 0; a < 4; ++a)
                #pragma unroll
                for (int c = 0; c < 4; ++c) acc[a][c] += qa[a] * va[c];
        }

        #pragma unroll
        for (int a = 0; a < 4; ++a) {
            float4 e;
            e.x = __expf(acc[a][0] * scale);
            e.y = __expf(acc[a][1] * scale);
            e.z = __expf(acc[a][2] * scale);
            e.w = __expf(acc[a][3] * scale);
            lacc[a] += (e.x + e.y) + (e.z + e.w);
            *(float4*)(ab + (size_t)(i0 + ty * 4 + a) * L_ + jt * 64 + tx * 4) = e;
        }
    }

    // reduce partial sums across tx (lanes differing in tid bits 0..3)
    #pragma unroll
    for (int m = 1; m <= 8; m <<= 1)
        #pragma unroll
        for (int a = 0; a < 4; ++a) lacc[a] += __shfl_xor(lacc[a], m, 64);

    if (tx == 0) {
        #pragma unroll
        for (int a = 0; a < 4; ++a)
            lpart[(size_t)jh * (B_ * L_) + (size_t)b * L_ + i0 + ty * 4 + a] = lacc[a];
    }
}

// K2: attn[row, :] /= (lpart0[row] + lpart1[row]), in place, float4 grid-stride.
__global__ __launch_bounds__(256) void normalize_kernel(
    float* __restrict__ attn, const float* __restrict__ lpart)
{
    const size_t nf4 = (size_t)B_ * L_ * L_ / 4;
    const size_t stride = (size_t)gridDim.x * 256;
    for (size_t idx = (size_t)blockIdx.x * 256 + threadIdx.x; idx < nf4; idx += stride) {
        const size_t row = idx >> 9;  // 512 float4 per attn row (L=2048)
        const float s = 1.0f / (lpart[row] + lpart[(size_t)B_ * L_ + row]);
        float4 t = ((const float4*)attn)[idx];
        t.x *= s; t.y *= s; t.z *= s; t.w *= s;
        ((float4*)attn)[idx] = t;
    }
}

// K3: out[b,j,d] = sum_i attn[b,i,j] * v[b,i,d]  (attn^T @ v per batch).
// Grid: B * 32 j-tiles = 256 blocks, 256 threads. Each thread: 4 j x 8 d.
__global__ __launch_bounds__(256) void out_gemm_kernel(
    const float* __restrict__ attn, const float* __restrict__ v,
    float* __restrict__ out)
{
    __shared__ float es[64 * 68];    // attn tile [i][j], stride 68 (16B-aligned)
    __shared__ float vsv[64 * 132];  // v tile [i][d], stride 132
    const int tid = threadIdx.x;
    const int b  = blockIdx.x >> 5;
    const int j0 = (blockIdx.x & 31) * 64;
    const int jg = tid >> 4, dg = tid & 15;
    const float* ab = attn + (size_t)b * L_ * L_;
    const float* vb = v + (size_t)b * L_ * D_;

    float acc[4][8];
    #pragma unroll
    for (int a = 0; a < 4; ++a)
        #pragma unroll
        for (int c = 0; c < 8; ++c) acc[a][c] = 0.f;

    for (int it = 0; it < 32; ++it) {
        __syncthreads();
        #pragma unroll
        for (int c = 0; c < 4; ++c) {  // attn tile: 64 rows x 16 f4
            const int idx = c * 256 + tid;
            const int rr = idx >> 4, c4 = idx & 15;
            const float4 t = ld4(ab + (size_t)(it * 64 + rr) * L_ + j0 + c4 * 4);
            *(float4*)(es + rr * 68 + c4 * 4) = t;
        }
        #pragma unroll
        for (int c = 0; c < 8; ++c) {  // v tile: 64 rows x 32 f4
            const int idx = c * 256 + tid;
            const int rr = idx >> 5, c4 = idx & 31;
            const float4 t = ld4(vb + (size_t)(it * 64 + rr) * D_ + c4 * 4);
            *(float4*)(vsv + rr * 132 + c4 * 4) = t;
        }
        __syncthreads();

        #pragma unroll 4
        for (int i = 0; i < 64; ++i) {
            const float4 e4 = ld4(es + i * 68 + jg * 4);
            const float4 v0 = ld4(vsv + i * 132 + dg * 8);
            const float4 v1 = ld4(vsv + i * 132 + dg * 8 + 4);
            const float ea[4] = {e4.x, e4.y, e4.z, e4.w};
            const float va[8] = {v0.x, v0.y, v0.z, v0.w, v1.x, v1.y, v1.z, v1.w};
            #pragma unroll
            for (int a = 0; a < 4; ++a)
                #pragma unroll
                for (int c = 0; c < 8; ++c) acc[a][c] += ea[a] * va[c];
        }
    }

    #pragma unroll
    for (int a = 0; a < 4; ++a) {
        float* op = out + (size_t)(b * L_ + j0 + jg * 4 + a) * D_ + dg * 8;
        const float4 t0 = make_float4(acc[a][0], acc[a][1], acc[a][2], acc[a][3]);
        const float4 t1 = make_float4(acc[a][4], acc[a][5], acc[a][6], acc[a][7]);
        *(float4*)op = t0;
        *(float4*)(op + 4) = t1;
    }
}

extern "C" void kernel_launch(void* const* d_in, const int* in_sizes, int n_in,
                              void* d_out, int out_size, void* d_ws, size_t ws_size,
                              hipStream_t stream)
{
    const float* q = (const float*)d_in[0];
    // d_in[1] = k: unused by the reference (scores come from q and v).
    const float* v = (const float*)d_in[2];
    float* out  = (float*)d_out;
    float* attn = out + (size_t)B_ * L_ * D_;  // outputs concatenated: [out | attn]

    // Row-sum partials: 2 * B * L floats = 128 KB. Prefer d_ws; if the workspace
    // is too small, park them in the out region (not written until K3).
    const size_t lbytes = (size_t)2 * B_ * L_ * sizeof(float);
    float* lpart = (ws_size >= lbytes) ? (float*)d_ws : out;

    score_exp_kernel<<<dim3(B_ * 64), 256, 0, stream>>>(q, v, attn, lpart);
    normalize_kernel<<<dim3(8192), 256, 0, stream>>>(attn, lpart);
    out_gemm_kernel<<<dim3(B_ * 32), 256, 0, stream>>>(attn, v, out);

    (void)in_sizes; (void)n_in; (void)out_size; (void)d_ws;
}

// Round 3
// 278.765 us; speedup vs baseline: 1.5965x; 1.5965x over previous
//
#include <hip/hip_runtime.h>
#include <hip/hip_bf16.h>

#define B_ 8
#define L_ 2048
#define D_ 128
#define SCALE 0.08838834764831845f  // 1/sqrt(128)

typedef __attribute__((ext_vector_type(8))) short short8;  // 8 bf16 = 4 VGPR (MFMA A/B frag)
typedef __attribute__((ext_vector_type(4))) float f32x4;   // MFMA C/D frag

// Device-global scratch (zero-init irrelevant: fully rewritten every call).
__device__ float          g_lpart[2 * B_ * L_];        // rowsum partials [jhalf][b*L+i]
__device__ unsigned short g_vT[(size_t)B_ * D_ * L_];  // v^T as bf16: [b][d][i]

static __device__ __forceinline__ float4 ld4(const float* p) { return *(const float4*)p; }
static __device__ __forceinline__ short bf(float f) {
    union { __hip_bfloat16 h; short s; } u; u.h = __float2bfloat16(f); return u.s;
}
static __device__ __forceinline__ short8 pack8(float4 a, float4 b) {
    short8 r;
    r[0] = bf(a.x); r[1] = bf(a.y); r[2] = bf(a.z); r[3] = bf(a.w);
    r[4] = bf(b.x); r[5] = bf(b.y); r[6] = bf(b.z); r[7] = bf(b.w);
    return r;
}
static __device__ __forceinline__ f32x4 mfma16(short8 a, short8 b, f32x4 c) {
    return __builtin_amdgcn_mfma_f32_16x16x32_bf16(a, b, c, 0, 0, 0);
}

// K0: g_vT[b][d][i] = bf16(v[b][i][d]).  256 blocks x 256 thr, 64i x 128d tiles.
__global__ __launch_bounds__(256) void vT_kernel(const float* __restrict__ v) {
    __shared__ float t[64 * 132];  // [i][d], pitch 132
    const int tid = threadIdx.x;
    const int b = blockIdx.x >> 5, i0 = (blockIdx.x & 31) * 64;
    const float* vb = v + ((size_t)b * L_ + i0) * D_;
    #pragma unroll
    for (int c = 0; c < 8; ++c) {
        const int g = c * 256 + tid, row = g >> 5, c4 = (g & 31) * 4;
        *(float4*)(t + row * 132 + c4) = ld4(vb + (size_t)row * D_ + c4);
    }
    __syncthreads();
    #pragma unroll
    for (int c = 0; c < 4; ++c) {
        const int g = c * 256 + tid, d = g >> 3, i8 = (g & 7) * 8;
        short8 r;
        #pragma unroll
        for (int j = 0; j < 8; ++j) r[j] = bf(t[(i8 + j) * 132 + d]);
        *(short8*)(void*)(g_vT + ((size_t)b * D_ + d) * L_ + i0 + i8) = r;
    }
}

// K1: e = exp(score*SCALE) via MFMA, written UNNORMALIZED to attn (fp32);
// per-row partial sums -> g_lpart.  Grid: b x 32 i-tiles x 2 j-halves = 512.
// Wave w owns 16 i-rows (w*16); D-frag: row(i)=quad*4+reg, col(j)=lane&15.
__global__ __launch_bounds__(256) void score_exp_kernel(const float* __restrict__ q,
                                                        const float* __restrict__ v,
                                                        float* __restrict__ attn) {
    __shared__ short vs[64 * 136];  // bf16 v rows [j_local][k], pitch 136
    const int tid = threadIdx.x;
    const int b = blockIdx.x >> 6, it = (blockIdx.x >> 1) & 31, jh = blockIdx.x & 1;
    const int i0 = it * 64;
    const int w = tid >> 6, lid = tid & 63, n16 = lid & 15, quad = lid >> 4;

    // A-frags: A[m=lane&15][k=quad*8+j], m -> q row i0+w*16+n16, k chunks c*32
    short8 qa[4];
    const float* qrow = q + ((size_t)b * L_ + i0 + w * 16 + n16) * D_ + quad * 8;
    #pragma unroll
    for (int c = 0; c < 4; ++c) qa[c] = pack8(ld4(qrow + c * 32), ld4(qrow + c * 32 + 4));

    float racc[4] = {0.f, 0.f, 0.f, 0.f};
    const float* vbp = v + (size_t)b * L_ * D_;
    float* ab = attn + (size_t)b * L_ * L_;

    for (int jt = 0; jt < 16; ++jt) {
        const int jb = jh * 1024 + jt * 64;
        __syncthreads();
        #pragma unroll
        for (int c = 0; c < 4; ++c) {  // stage 64 v rows as bf16
            const int g = c * 256 + tid, row = g >> 4, col8 = (g & 15) * 8;
            const float* src = vbp + (size_t)(jb + row) * D_ + col8;
            *(short8*)(vs + row * 136 + col8) = pack8(ld4(src), ld4(src + 4));
        }
        __syncthreads();
        #pragma unroll
        for (int jc = 0; jc < 4; ++jc) {
            f32x4 d = {0.f, 0.f, 0.f, 0.f};
            #pragma unroll
            for (int c = 0; c < 4; ++c) {
                const short8 vf = *(const short8*)(vs + (jc * 16 + n16) * 136 + c * 32 + quad * 8);
                d = mfma16(qa[c], vf, d);
            }
            float* ap = ab + (size_t)(i0 + w * 16 + quad * 4) * L_ + jb + jc * 16 + n16;
            #pragma unroll
            for (int r = 0; r < 4; ++r) {
                const float e = __expf(d[r] * SCALE);
                racc[r] += e;
                ap[(size_t)r * L_] = e;
            }
        }
    }
    // sum over the 16 j-lanes (tid bits 0..3)
    #pragma unroll
    for (int m = 1; m <= 8; m <<= 1)
        #pragma unroll
        for (int r = 0; r < 4; ++r) racc[r] += __shfl_xor(racc[r], m, 64);
    if (n16 == 0) {
        const float4 o = make_float4(racc[0], racc[1], racc[2], racc[3]);
        *(float4*)(g_lpart + jh * (B_ * L_) + b * L_ + i0 + w * 16 + quad * 4) = o;
    }
}

// K2: attn[row,:] /= (lpart0[row]+lpart1[row]), in place.  (Verbatim from R1 - passed.)
__global__ __launch_bounds__(256) void normalize_kernel(float* __restrict__ attn) {
    const size_t nf4 = (size_t)B_ * L_ * L_ / 4;
    const size_t stride = (size_t)gridDim.x * 256;
    for (size_t idx = (size_t)blockIdx.x * 256 + threadIdx.x; idx < nf4; idx += stride) {
        const size_t row = idx >> 9;  // 512 float4 per attn row
        const float s = 1.0f / (g_lpart[row] + g_lpart[(size_t)B_ * L_ + row]);
        float4 t = ((const float4*)attn)[idx];
        t.x *= s; t.y *= s; t.z *= s; t.w *= s;
        ((float4*)attn)[idx] = t;
    }
}

// K3: out[b,j,d] = sum_i attn[b,i,j] * v[b,i,d] via MFMA.
// Grid: b x 64 j-tiles(32) = 512 blocks. Wave w: jg=w&1 (16 j), dgrp=w>>1 (64 d).
// A = attn^T tile (transposed into LDS bf16), B = vT tile from g_vT.
__global__ __launch_bounds__(256) void out_gemm_kernel(const float* __restrict__ attn,
                                                       float* __restrict__ out) {
    __shared__ short aT[32 * 72];   // [j_local][i_local], pitch 72
    __shared__ short vT[128 * 72];  // [d][i_local], pitch 72
    const int tid = threadIdx.x;
    const int b = blockIdx.x >> 6, j0 = (blockIdx.x & 63) * 32;
    const int w = tid >> 6, lid = tid & 63, n16 = lid & 15, quad = lid >> 4;
    const int jg = w & 1, dgrp = w >> 1;
    const float* ab = attn + (size_t)b * L_ * L_;
    const unsigned short* vTb = g_vT + (size_t)b * D_ * L_;

    f32x4 oacc[4];
    #pragma unroll
    for (int dc = 0; dc < 4; ++dc) oacc[dc] = (f32x4){0.f, 0.f, 0.f, 0.f};

    for (int i0 = 0; i0 < L_; i0 += 64) {
        __syncthreads();
        #pragma unroll
        for (int c = 0; c < 2; ++c) {  // attn tile [64 i][32 j] -> aT bf16 transposed
            const int g = c * 256 + tid, il = g >> 3, jf = g & 7;
            const float4 t = ld4(ab + (size_t)(i0 + il) * L_ + j0 + jf * 4);
            aT[(jf * 4 + 0) * 72 + il] = bf(t.x);
            aT[(jf * 4 + 1) * 72 + il] = bf(t.y);
            aT[(jf * 4 + 2) * 72 + il] = bf(t.z);
            aT[(jf * 4 + 3) * 72 + il] = bf(t.w);
        }
        #pragma unroll
        for (int c = 0; c < 4; ++c) {  // vT tile [128 d][64 i] (already bf16)
            const int g = c * 256 + tid, d = g >> 3, ic = (g & 7) * 8;
            *(short8*)(vT + d * 72 + ic) =
                *(const short8*)(const void*)(vTb + (size_t)d * L_ + i0 + ic);
        }
        __syncthreads();
        #pragma unroll
        for (int kc = 0; kc < 2; ++kc) {
            const short8 af = *(const short8*)(aT + (jg * 16 + n16) * 72 + kc * 32 + quad * 8);
            #pragma unroll
            for (int dc = 0; dc < 4; ++dc) {
                const short8 vf = *(const short8*)(
                    vT + (dgrp * 64 + dc * 16 + n16) * 72 + kc * 32 + quad * 8);
                oacc[dc] = mfma16(af, vf, oacc[dc]);
            }
        }
    }
    // D[row=j_local=quad*4+r][col=d=n16] per dc chunk
    #pragma unroll
    for (int dc = 0; dc < 4; ++dc)
        #pragma unroll
        for (int r = 0; r < 4; ++r)
            out[((size_t)b * L_ + j0 + jg * 16 + quad * 4 + r) * D_ + dgrp * 64 + dc * 16 + n16] =
                oacc[dc][r];
}

extern "C" void kernel_launch(void* const* d_in, const int* in_sizes, int n_in,
                              void* d_out, int out_size, void* d_ws, size_t ws_size,
                              hipStream_t stream) {
    const float* q = (const float*)d_in[0];
    // d_in[1] = k: unused by the reference (scores come from q and v).
    const float* v = (const float*)d_in[2];
    float* out  = (float*)d_out;
    float* attn = out + (size_t)B_ * L_ * D_;  // outputs concatenated: [out | attn]

    vT_kernel<<<dim3(B_ * 32), 256, 0, stream>>>(v);
    score_exp_kernel<<<dim3(B_ * 64), 256, 0, stream>>>(q, v, attn);
    normalize_kernel<<<dim3(8192), 256, 0, stream>>>(attn);
    out_gemm_kernel<<<dim3(B_ * 64), 256, 0, stream>>>(attn, out);

    (void)in_sizes; (void)n_in; (void)out_size; (void)d_ws; (void)ws_size;
}